// Round 2
// baseline (233.443 us; speedup 1.0000x reference)
//
#include <hip/hip_runtime.h>
#include <hip/hip_bf16.h>

#define SEQ 1024
#define EMBD 128

typedef __attribute__((ext_vector_type(8))) short s16x8;
typedef __attribute__((ext_vector_type(4))) float f32x4;
typedef __attribute__((ext_vector_type(4))) unsigned int u32x4;

// bf16 weight offsets in workspace (elements)
#define W1_OFF 0
#define W2_OFF (512 * 640)
#define W3_OFF (W2_OFF + 256 * 512)
#define W4_OFF (W3_OFF + 128 * 256)
#define WTOT   (W4_OFF + 38 * 128)

__device__ __forceinline__ unsigned int f2bf(float f) {
    unsigned int u = __float_as_uint(f);
    return (u + 0x7fffu + ((u >> 16) & 1u)) >> 16;   // RNE
}

__global__ void convert_w_kernel(const float* __restrict__ w1, const float* __restrict__ w2,
                                 const float* __restrict__ w3, const float* __restrict__ w4,
                                 unsigned short* __restrict__ dst) {
    int i = blockIdx.x * blockDim.x + threadIdx.x;
    if (i >= WTOT) return;
    float f;
    if (i < W2_OFF)      f = w1[i];
    else if (i < W3_OFF) f = w2[i - W2_OFF];
    else if (i < W4_OFF) f = w3[i - W3_OFF];
    else                 f = w4[i - W4_OFF];
    dst[i] = (unsigned short)f2bf(f);
}

// 32-row tile LDS layout (bytes), 48 KB total -> 3 blocks/CU:
//   region A @ 0     (16384): x tile (36 rows x 256B = 9216B) -> later h2 (32 x 512B)
//   region B @ 16384 (32768): h1 (32 x 1024B)                 -> later h3 (32 x 256B)
#define RB 16384

__launch_bounds__(512, 6)
__global__ void fused_mlp(const int* __restrict__ tok,
                          const float* __restrict__ emb,
                          const unsigned short* __restrict__ wbf,
                          const float* __restrict__ b1,
                          const float* __restrict__ b2,
                          const float* __restrict__ b3,
                          const float* __restrict__ b4,
                          float* __restrict__ out) {
    __shared__ char smem[49152];
    const int tid  = threadIdx.x;
    const int lane = tid & 63;
    const int wave = tid >> 6;
    const int l15  = lane & 15;
    const int l4   = lane >> 4;                // 0..3
    const int r0   = blockIdx.x * 32;          // first output row of this block
    const int s0   = r0 & (SEQ - 1);
    const int bat  = r0 >> 10;

    // ---------- stage embedded x tile: rows s0-2 .. s0+33 (36 rows) x 128 dims, bf16
    for (int chunk = tid; chunk < 36 * 16; chunk += 512) {
        const int row = chunk >> 4;            // 0..35
        const int c   = chunk & 15;            // 16B chunk within row (8 bf16)
        const int sp  = s0 - 2 + row;
        u32x4 v = {0u, 0u, 0u, 0u};
        if (sp >= 0 && sp < SEQ) {
            const int t = tok[bat * SEQ + sp];
            const float* e = emb + t * EMBD + c * 8;
            unsigned int p0 = f2bf(e[0]) | (f2bf(e[1]) << 16);
            unsigned int p1 = f2bf(e[2]) | (f2bf(e[3]) << 16);
            unsigned int p2 = f2bf(e[4]) | (f2bf(e[5]) << 16);
            unsigned int p3 = f2bf(e[6]) | (f2bf(e[7]) << 16);
            v = (u32x4){p0, p1, p2, p3};
        }
        int byte = row * 256 + c * 16;
        byte ^= (row & 7) << 4;
        *reinterpret_cast<u32x4*>(smem + byte) = v;
    }
    __syncthreads();

    // ---------- GEMM1: [32,640] x W1^T[640,512] -> h1 bf16 in LDS (region B)
    {
        f32x4 acc[2][4];
        #pragma unroll
        for (int m = 0; m < 2; ++m)
            #pragma unroll
            for (int n = 0; n < 4; ++n) acc[m][n] = (f32x4){0.f, 0.f, 0.f, 0.f};
        const int nb = wave * 64;              // this wave's N base (512 / 8 waves)
        for (int ks = 0; ks < 20; ++ks) {
            const int j    = ks >> 2;          // context offset 0..4
            const int doff = (ks & 3) * 32;    // dim offset within embedding
            const int kg   = ks * 32 + 8 * l4; // global k of this lane's 8 elems
            s16x8 a[2];
            #pragma unroll
            for (int m = 0; m < 2; ++m) {
                const int row = m * 16 + l15 + j;      // x row (shifted by context)
                int byte = row * 256 + (doff + 8 * l4) * 2;
                byte ^= (row & 7) << 4;
                a[m] = *reinterpret_cast<const s16x8*>(smem + byte);
            }
            #pragma unroll
            for (int n = 0; n < 4; ++n) {
                const int col = nb + n * 16 + l15;
                s16x8 b = *reinterpret_cast<const s16x8*>(wbf + W1_OFF + col * 640 + kg);
                #pragma unroll
                for (int m = 0; m < 2; ++m)
                    acc[m][n] = __builtin_amdgcn_mfma_f32_16x16x32_bf16(a[m], b, acc[m][n], 0, 0, 0);
            }
        }
        #pragma unroll
        for (int n = 0; n < 4; ++n) {
            const int col  = nb + n * 16 + l15;
            const float bi = b1[col];
            #pragma unroll
            for (int m = 0; m < 2; ++m)
                #pragma unroll
                for (int q = 0; q < 4; ++q) {
                    const int row = m * 16 + l4 * 4 + q;
                    float v = fmaxf(acc[m][n][q] + bi, 0.f);
                    int byte = RB + row * 1024 + col * 2;
                    byte ^= (row & 7) << 4;
                    *reinterpret_cast<unsigned short*>(smem + byte) = (unsigned short)f2bf(v);
                }
        }
    }
    __syncthreads();

    // ---------- GEMM2: [32,512] x W2^T[512,256] -> h2 bf16 in LDS (region A)
    {
        f32x4 acc[2][2];
        #pragma unroll
        for (int m = 0; m < 2; ++m)
            #pragma unroll
            for (int n = 0; n < 2; ++n) acc[m][n] = (f32x4){0.f, 0.f, 0.f, 0.f};
        const int nb = wave * 32;              // 256 / 8 waves
        for (int ks = 0; ks < 16; ++ks) {
            const int kg = ks * 32 + 8 * l4;
            s16x8 a[2];
            #pragma unroll
            for (int m = 0; m < 2; ++m) {
                const int row = m * 16 + l15;
                int byte = RB + row * 1024 + kg * 2;
                byte ^= (row & 7) << 4;
                a[m] = *reinterpret_cast<const s16x8*>(smem + byte);
            }
            #pragma unroll
            for (int n = 0; n < 2; ++n) {
                const int col = nb + n * 16 + l15;
                s16x8 b = *reinterpret_cast<const s16x8*>(wbf + W2_OFF + col * 512 + kg);
                #pragma unroll
                for (int m = 0; m < 2; ++m)
                    acc[m][n] = __builtin_amdgcn_mfma_f32_16x16x32_bf16(a[m], b, acc[m][n], 0, 0, 0);
            }
        }
        #pragma unroll
        for (int n = 0; n < 2; ++n) {
            const int col  = nb + n * 16 + l15;
            const float bi = b2[col];
            #pragma unroll
            for (int m = 0; m < 2; ++m)
                #pragma unroll
                for (int q = 0; q < 4; ++q) {
                    const int row = m * 16 + l4 * 4 + q;
                    float v = fmaxf(acc[m][n][q] + bi, 0.f);
                    int byte = row * 512 + col * 2;
                    byte ^= (row & 7) << 4;
                    *reinterpret_cast<unsigned short*>(smem + byte) = (unsigned short)f2bf(v);
                }
        }
    }
    __syncthreads();

    // ---------- GEMM3: [32,256] x W3^T[256,128] -> h3 bf16 in LDS (region B)
    {
        f32x4 acc[2];
        #pragma unroll
        for (int m = 0; m < 2; ++m) acc[m] = (f32x4){0.f, 0.f, 0.f, 0.f};
        const int nb = wave * 16;              // 128 / 8 waves
        for (int ks = 0; ks < 8; ++ks) {
            const int kg = ks * 32 + 8 * l4;
            const int col = nb + l15;
            s16x8 b = *reinterpret_cast<const s16x8*>(wbf + W3_OFF + col * 256 + kg);
            #pragma unroll
            for (int m = 0; m < 2; ++m) {
                const int row = m * 16 + l15;
                int byte = row * 512 + kg * 2;
                byte ^= (row & 7) << 4;
                s16x8 a = *reinterpret_cast<const s16x8*>(smem + byte);
                acc[m] = __builtin_amdgcn_mfma_f32_16x16x32_bf16(a, b, acc[m], 0, 0, 0);
            }
        }
        const int col  = nb + l15;
        const float bi = b3[col];
        #pragma unroll
        for (int m = 0; m < 2; ++m)
            #pragma unroll
            for (int q = 0; q < 4; ++q) {
                const int row = m * 16 + l4 * 4 + q;
                float v = fmaxf(acc[m][q] + bi, 0.f);
                int byte = RB + row * 256 + col * 2;
                byte ^= (row & 7) << 4;
                *reinterpret_cast<unsigned short*>(smem + byte) = (unsigned short)f2bf(v);
            }
    }
    __syncthreads();

    // ---------- GEMM4: [32,128] x W4^T[128,38] -> out fp32 (waves 0..5: (m,n) tiles)
    if (wave < 6) {
        f32x4 acc = (f32x4){0.f, 0.f, 0.f, 0.f};
        const int m = wave & 1;
        const int n = wave >> 1;               // 0..2
        const int col = n * 16 + l15;
        for (int ks = 0; ks < 4; ++ks) {
            const int kg  = ks * 32 + 8 * l4;
            const int row = m * 16 + l15;
            int byte = RB + row * 256 + kg * 2;
            byte ^= (row & 7) << 4;
            s16x8 a = *reinterpret_cast<const s16x8*>(smem + byte);
            s16x8 b = {0, 0, 0, 0, 0, 0, 0, 0};
            if (col < 38)
                b = *reinterpret_cast<const s16x8*>(wbf + W4_OFF + col * 128 + kg);
            acc = __builtin_amdgcn_mfma_f32_16x16x32_bf16(a, b, acc, 0, 0, 0);
        }
        if (col < 38) {
            const float bi = b4[col];
            #pragma unroll
            for (int q = 0; q < 4; ++q) {
                const int rg = r0 + m * 16 + l4 * 4 + q;
                out[rg * 38 + col] = acc[q] + bi;
            }
        }
    }
}

extern "C" void kernel_launch(void* const* d_in, const int* in_sizes, int n_in,
                              void* d_out, int out_size, void* d_ws, size_t ws_size,
                              hipStream_t stream) {
    const int*   tok = (const int*)d_in[0];
    const float* emb = (const float*)d_in[1];
    const float* W1  = (const float*)d_in[2];
    const float* b1  = (const float*)d_in[3];
    const float* W2  = (const float*)d_in[4];
    const float* b2  = (const float*)d_in[5];
    const float* W3  = (const float*)d_in[6];
    const float* b3  = (const float*)d_in[7];
    const float* W4  = (const float*)d_in[8];
    const float* b4  = (const float*)d_in[9];
    float* out = (float*)d_out;
    unsigned short* wbf = (unsigned short*)d_ws;

    convert_w_kernel<<<(WTOT + 255) / 256, 256, 0, stream>>>(W1, W2, W3, W4, wbf);
    fused_mlp<<<2048, 512, 0, stream>>>(tok, emb, wbf, b1, b2, b3, b4, out);
}

// Round 3
// 198.805 us; speedup vs baseline: 1.1742x; 1.1742x over previous
//
#include <hip/hip_runtime.h>
#include <hip/hip_bf16.h>

#define SEQ 1024
#define EMBD 128

typedef __attribute__((ext_vector_type(8))) short s16x8;
typedef __attribute__((ext_vector_type(4))) float f32x4;

// bf16 data offsets in workspace (elements)
#define W1_OFF 0
#define W2_OFF (512 * 640)
#define W3_OFF (W2_OFF + 256 * 512)
#define W4_OFF (W3_OFF + 128 * 256)
#define EMB_OFF (W4_OFF + 38 * 128)
#define WTOT    (EMB_OFF + 38 * 128)

__device__ __forceinline__ unsigned int f2bf(float f) {
    unsigned int u = __float_as_uint(f);
    return (u + 0x7fffu + ((u >> 16) & 1u)) >> 16;   // RNE
}

__global__ void convert_w_kernel(const float* __restrict__ w1, const float* __restrict__ w2,
                                 const float* __restrict__ w3, const float* __restrict__ w4,
                                 const float* __restrict__ emb,
                                 unsigned short* __restrict__ dst) {
    int i = blockIdx.x * blockDim.x + threadIdx.x;
    if (i >= WTOT) return;
    float f;
    if (i < W2_OFF)       f = w1[i];
    else if (i < W3_OFF)  f = w2[i - W2_OFF];
    else if (i < W4_OFF)  f = w3[i - W3_OFF];
    else if (i < EMB_OFF) f = w4[i - W4_OFF];
    else                  f = emb[i - EMB_OFF];
    dst[i] = (unsigned short)f2bf(f);
}

// LDS layout (bytes), 64 KB total -> 2 blocks/CU:
//   region A @ 0     (32768): x tile (68 rows x 256B = 17408) -> later h2 (64 x 512B)
//   region B @ 32768 (32768): h1 half-tile (64 rows x 256 cols, 512B stride)
//                             -> later h3 (64 x 256B)
#define HB 32768

__device__ __forceinline__ s16x8 lds_a(const char* smem, int byte) {
    return *reinterpret_cast<const s16x8*>(smem + byte);
}

__launch_bounds__(512, 4)
__global__ void fused_mlp(const int* __restrict__ tok,
                          const unsigned short* __restrict__ wbf,
                          const float* __restrict__ b1,
                          const float* __restrict__ b2,
                          const float* __restrict__ b3,
                          const float* __restrict__ b4,
                          float* __restrict__ out) {
    __shared__ char smem[65536];
    const int tid  = threadIdx.x;
    const int lane = tid & 63;
    const int wave = tid >> 6;
    const int l15  = lane & 15;
    const int l4   = lane >> 4;                // 0..3
    const int r0   = blockIdx.x * 64;          // first output row of this block
    const int s0   = r0 & (SEQ - 1);
    const int bat  = r0 >> 10;

    // ---------- stage embedded x tile: rows s0-2 .. s0+65 (68 rows) x 128 dims, bf16
    {
        const unsigned short* embf = wbf + EMB_OFF;
        for (int chunk = tid; chunk < 68 * 16; chunk += 512) {
            const int row = chunk >> 4;        // 0..67
            const int c   = chunk & 15;        // 16B chunk (8 bf16)
            const int sp  = s0 - 2 + row;
            s16x8 v = {0, 0, 0, 0, 0, 0, 0, 0};
            if (sp >= 0 && sp < SEQ) {
                const int t = tok[bat * SEQ + sp];
                v = *reinterpret_cast<const s16x8*>(embf + t * EMBD + c * 8);
            }
            int byte = row * 256 + c * 16;
            byte ^= (row & 7) << 4;
            *reinterpret_cast<s16x8*>(smem + byte) = v;
        }
    }
    __syncthreads();

    f32x4 acc2[4][2];                          // GEMM2 accumulator, carried across passes
    #pragma unroll
    for (int m = 0; m < 4; ++m)
        #pragma unroll
        for (int n = 0; n < 2; ++n) acc2[m][n] = (f32x4){0.f, 0.f, 0.f, 0.f};

    #pragma unroll
    for (int p = 0; p < 2; ++p) {
        // ---------- GEMM1 pass p: [64,640] x W1^T[:, 256p..256p+255] -> h1 half in LDS B
        {
            f32x4 acc[4][2];
            #pragma unroll
            for (int m = 0; m < 4; ++m)
                #pragma unroll
                for (int n = 0; n < 2; ++n) acc[m][n] = (f32x4){0.f, 0.f, 0.f, 0.f};
            const int colg = p * 256 + wave * 32 + l15;
            const unsigned short* bp0 = wbf + W1_OFF + colg * 640 + 8 * l4;
            const unsigned short* bp1 = bp0 + 16 * 640;
            s16x8 ring[4][2];
            #pragma unroll
            for (int t = 0; t < 4; ++t) {
                ring[t][0] = *reinterpret_cast<const s16x8*>(bp0 + t * 32);
                ring[t][1] = *reinterpret_cast<const s16x8*>(bp1 + t * 32);
            }
            #pragma unroll
            for (int ks = 0; ks < 20; ++ks) {
                const int j    = ks >> 2;          // context offset 0..4
                const int doff = (ks & 3) * 32;    // dim offset within embedding
                s16x8 a[4];
                #pragma unroll
                for (int m = 0; m < 4; ++m) {
                    const int row = m * 16 + l15 + j;
                    int byte = row * 256 + (doff + 8 * l4) * 2;
                    byte ^= (row & 7) << 4;
                    a[m] = lds_a(smem, byte);
                }
                s16x8 c0 = ring[ks & 3][0];
                s16x8 c1 = ring[ks & 3][1];
                if (ks < 16) {
                    ring[ks & 3][0] = *reinterpret_cast<const s16x8*>(bp0 + (ks + 4) * 32);
                    ring[ks & 3][1] = *reinterpret_cast<const s16x8*>(bp1 + (ks + 4) * 32);
                }
                #pragma unroll
                for (int m = 0; m < 4; ++m)
                    acc[m][0] = __builtin_amdgcn_mfma_f32_16x16x32_bf16(a[m], c0, acc[m][0], 0, 0, 0);
                #pragma unroll
                for (int m = 0; m < 4; ++m)
                    acc[m][1] = __builtin_amdgcn_mfma_f32_16x16x32_bf16(a[m], c1, acc[m][1], 0, 0, 0);
            }
            // epilogue: bias + relu -> bf16 -> LDS region B (local cols 0..255)
            #pragma unroll
            for (int n = 0; n < 2; ++n) {
                const int col = p * 256 + wave * 32 + n * 16 + l15;
                const int lc  = wave * 32 + n * 16 + l15;
                const float bi = b1[col];
                #pragma unroll
                for (int m = 0; m < 4; ++m)
                    #pragma unroll
                    for (int q = 0; q < 4; ++q) {
                        const int row = m * 16 + l4 * 4 + q;
                        float v = fmaxf(acc[m][n][q] + bi, 0.f);
                        int byte = HB + row * 512 + lc * 2;
                        byte ^= (row & 7) << 4;
                        *reinterpret_cast<unsigned short*>(smem + byte) = (unsigned short)f2bf(v);
                    }
            }
        }
        __syncthreads();

        // ---------- GEMM2 partial: [64,256] (h1 half) x W2^T[256p.., 256] -> acc2
        {
            const int col = wave * 32 + l15;
            const unsigned short* bp0 = wbf + W2_OFF + col * 512 + p * 256 + 8 * l4;
            const unsigned short* bp1 = bp0 + 16 * 512;
            s16x8 ring[4][2];
            #pragma unroll
            for (int t = 0; t < 4; ++t) {
                ring[t][0] = *reinterpret_cast<const s16x8*>(bp0 + t * 32);
                ring[t][1] = *reinterpret_cast<const s16x8*>(bp1 + t * 32);
            }
            #pragma unroll
            for (int ks = 0; ks < 8; ++ks) {
                const int kl = ks * 32 + 8 * l4;   // local k within h1 half
                s16x8 a[4];
                #pragma unroll
                for (int m = 0; m < 4; ++m) {
                    const int row = m * 16 + l15;
                    int byte = HB + row * 512 + kl * 2;
                    byte ^= (row & 7) << 4;
                    a[m] = lds_a(smem, byte);
                }
                s16x8 c0 = ring[ks & 3][0];
                s16x8 c1 = ring[ks & 3][1];
                if (ks < 4) {
                    ring[ks & 3][0] = *reinterpret_cast<const s16x8*>(bp0 + (ks + 4) * 32);
                    ring[ks & 3][1] = *reinterpret_cast<const s16x8*>(bp1 + (ks + 4) * 32);
                }
                #pragma unroll
                for (int m = 0; m < 4; ++m)
                    acc2[m][0] = __builtin_amdgcn_mfma_f32_16x16x32_bf16(a[m], c0, acc2[m][0], 0, 0, 0);
                #pragma unroll
                for (int m = 0; m < 4; ++m)
                    acc2[m][1] = __builtin_amdgcn_mfma_f32_16x16x32_bf16(a[m], c1, acc2[m][1], 0, 0, 0);
            }
        }
        __syncthreads();   // p=0: before GEMM1 pass1 overwrites h1; p=1: before h2 write below
    }

    // ---------- GEMM2 epilogue: bias + relu -> h2 bf16 in LDS region A
    {
        #pragma unroll
        for (int n = 0; n < 2; ++n) {
            const int col  = wave * 32 + n * 16 + l15;
            const float bi = b2[col];
            #pragma unroll
            for (int m = 0; m < 4; ++m)
                #pragma unroll
                for (int q = 0; q < 4; ++q) {
                    const int row = m * 16 + l4 * 4 + q;
                    float v = fmaxf(acc2[m][n][q] + bi, 0.f);
                    int byte = row * 512 + col * 2;
                    byte ^= (row & 7) << 4;
                    *reinterpret_cast<unsigned short*>(smem + byte) = (unsigned short)f2bf(v);
                }
        }
    }
    __syncthreads();

    // ---------- GEMM3: [64,256] x W3^T[256,128] -> h3 bf16 in LDS region B
    {
        f32x4 acc[4];
        #pragma unroll
        for (int m = 0; m < 4; ++m) acc[m] = (f32x4){0.f, 0.f, 0.f, 0.f};
        const int col = wave * 16 + l15;
        const unsigned short* bp = wbf + W3_OFF + col * 256 + 8 * l4;
        s16x8 ring[4];
        #pragma unroll
        for (int t = 0; t < 4; ++t)
            ring[t] = *reinterpret_cast<const s16x8*>(bp + t * 32);
        #pragma unroll
        for (int ks = 0; ks < 8; ++ks) {
            const int kl = ks * 32 + 8 * l4;
            s16x8 c0 = ring[ks & 3];
            if (ks < 4)
                ring[ks & 3] = *reinterpret_cast<const s16x8*>(bp + (ks + 4) * 32);
            #pragma unroll
            for (int m = 0; m < 4; ++m) {
                const int row = m * 16 + l15;
                int byte = row * 512 + kl * 2;
                byte ^= (row & 7) << 4;
                s16x8 a = lds_a(smem, byte);
                acc[m] = __builtin_amdgcn_mfma_f32_16x16x32_bf16(a, c0, acc[m], 0, 0, 0);
            }
        }
        const float bi = b3[col];
        #pragma unroll
        for (int m = 0; m < 4; ++m)
            #pragma unroll
            for (int q = 0; q < 4; ++q) {
                const int row = m * 16 + l4 * 4 + q;
                float v = fmaxf(acc[m][q] + bi, 0.f);
                int byte = HB + row * 256 + col * 2;
                byte ^= (row & 7) << 4;
                *reinterpret_cast<unsigned short*>(smem + byte) = (unsigned short)f2bf(v);
            }
    }
    __syncthreads();

    // ---------- GEMM4: [64,128] x W4^T[128,38] -> out fp32 (waves 0..3, one M-tile each)
    if (wave < 4) {
        f32x4 acc[3];
        #pragma unroll
        for (int n = 0; n < 3; ++n) acc[n] = (f32x4){0.f, 0.f, 0.f, 0.f};
        const int m = wave;
        #pragma unroll
        for (int ks = 0; ks < 4; ++ks) {
            const int kl  = ks * 32 + 8 * l4;
            const int row = m * 16 + l15;
            int byte = HB + row * 256 + kl * 2;
            byte ^= (row & 7) << 4;
            s16x8 a = lds_a(smem, byte);
            #pragma unroll
            for (int n = 0; n < 3; ++n) {
                const int col = n * 16 + l15;
                s16x8 b = {0, 0, 0, 0, 0, 0, 0, 0};
                if (col < 38)
                    b = *reinterpret_cast<const s16x8*>(wbf + W4_OFF + col * 128 + kl);
                acc[n] = __builtin_amdgcn_mfma_f32_16x16x32_bf16(a, b, acc[n], 0, 0, 0);
            }
        }
        #pragma unroll
        for (int n = 0; n < 3; ++n) {
            const int col = n * 16 + l15;
            if (col < 38) {
                const float bi = b4[col];
                #pragma unroll
                for (int q = 0; q < 4; ++q) {
                    const int rg = r0 + m * 16 + l4 * 4 + q;
                    out[rg * 38 + col] = acc[n][q] + bi;
                }
            }
        }
    }
}

extern "C" void kernel_launch(void* const* d_in, const int* in_sizes, int n_in,
                              void* d_out, int out_size, void* d_ws, size_t ws_size,
                              hipStream_t stream) {
    const int*   tok = (const int*)d_in[0];
    const float* emb = (const float*)d_in[1];
    const float* W1  = (const float*)d_in[2];
    const float* b1  = (const float*)d_in[3];
    const float* W2  = (const float*)d_in[4];
    const float* b2  = (const float*)d_in[5];
    const float* W3  = (const float*)d_in[6];
    const float* b3  = (const float*)d_in[7];
    const float* W4  = (const float*)d_in[8];
    const float* b4  = (const float*)d_in[9];
    float* out = (float*)d_out;
    unsigned short* wbf = (unsigned short*)d_ws;

    convert_w_kernel<<<(WTOT + 255) / 256, 256, 0, stream>>>(W1, W2, W3, W4, emb, wbf);
    fused_mlp<<<1024, 512, 0, stream>>>(tok, wbf, b1, b2, b3, b4, out);
}

// Round 4
// 121.005 us; speedup vs baseline: 1.9292x; 1.6430x over previous
//
#include <hip/hip_runtime.h>
#include <hip/hip_bf16.h>

#define SEQ 1024
#define EMBD 128

typedef __attribute__((ext_vector_type(8))) short s16x8;
typedef __attribute__((ext_vector_type(4))) float f32x4;

// packed bf16 offsets in workspace (elements)
// W layouts are MFMA-B-fragment linear: ((ctile*KC + kc)*64 + lane)*8
#define W1P 0
#define W2P (W1P + 32 * 20 * 512)
#define W3P (W2P + 16 * 16 * 512)
#define W4P (W3P + 8 * 8 * 512)
#define EMBP (W4P + 3 * 4 * 512)
#define TOTE (EMBP + 38 * 128)

#define G1N (32 * 20 * 64)
#define G2N (16 * 16 * 64)
#define G3N (8 * 8 * 64)
#define G4N (3 * 4 * 64)
#define GW  (G1N + G2N + G3N + G4N)
#define GEN (38 * 128 / 8)
#define GTOT (GW + GEN)

__device__ __forceinline__ unsigned int f2bf(float f) {
    unsigned int u = __float_as_uint(f);
    return (u + 0x7fffu + ((u >> 16) & 1u)) >> 16;   // RNE
}

__global__ void pack_kernel(const float* __restrict__ w1, const float* __restrict__ w2,
                            const float* __restrict__ w3, const float* __restrict__ w4,
                            const float* __restrict__ emb, unsigned short* __restrict__ dst) {
    const int g = blockIdx.x * 256 + threadIdx.x;
    if (g >= GTOT) return;
    unsigned short o[8];
    if (g < GW) {
        const float* w; int K, N, KC, base, gl;
        if (g < G1N)              { w = w1; K = 640; N = 512; KC = 20; base = W1P; gl = g; }
        else if (g < G1N + G2N)   { w = w2; K = 512; N = 256; KC = 16; base = W2P; gl = g - G1N; }
        else if (g < G1N+G2N+G3N) { w = w3; K = 256; N = 128; KC = 8;  base = W3P; gl = g - G1N - G2N; }
        else                      { w = w4; K = 128; N = 38;  KC = 4;  base = W4P; gl = g - G1N - G2N - G3N; }
        const int lane = gl & 63;
        const int t    = gl >> 6;
        const int ct   = t / KC;
        const int kc   = t - ct * KC;
        const int col  = ct * 16 + (lane & 15);
        const int k0   = kc * 32 + (lane >> 4) * 8;
        #pragma unroll
        for (int e = 0; e < 8; ++e)
            o[e] = (col < N) ? (unsigned short)f2bf(w[col * K + k0 + e]) : (unsigned short)0;
        *reinterpret_cast<s16x8*>(dst + base + (size_t)gl * 8) = *reinterpret_cast<s16x8*>(o);
    } else {
        const int gl = g - GW;
        #pragma unroll
        for (int e = 0; e < 8; ++e)
            o[e] = (unsigned short)f2bf(emb[gl * 8 + e]);
        *reinterpret_cast<s16x8*>(dst + EMBP + (size_t)gl * 8) = *reinterpret_cast<s16x8*>(o);
    }
}

// LDS layout (bytes), 64 KB total -> 2 blocks/CU:
//   region A @ 0     (32768): x tile (68 rows x 256B) -> later h2 (64 x 512B)
//   region B @ 32768 (32768): h1 half (64 rows x 256 cols, 512B stride) -> later h3 (64 x 256B)
#define HB 32768

__launch_bounds__(512, 4)
__global__ void fused_mlp(const int* __restrict__ tok,
                          const unsigned short* __restrict__ wbf,
                          const float* __restrict__ b1,
                          const float* __restrict__ b2,
                          const float* __restrict__ b3,
                          const float* __restrict__ b4,
                          float* __restrict__ out) {
    __shared__ char smem[65536];
    const int tid  = threadIdx.x;
    const int lane = tid & 63;
    const int wave = tid >> 6;
    const int l15  = lane & 15;
    const int l4   = lane >> 4;                // 0..3
    const int r0   = blockIdx.x * 64;
    const int s0   = r0 & (SEQ - 1);
    const int bat  = r0 >> 10;

    // ---------- stage embedded x tile: rows s0-2 .. s0+65 (68 rows) x 128 dims, bf16
    {
        const unsigned short* embf = wbf + EMBP;
        for (int chunk = tid; chunk < 68 * 16; chunk += 512) {
            const int row = chunk >> 4;
            const int c   = chunk & 15;
            const int sp  = s0 - 2 + row;
            s16x8 v = {0, 0, 0, 0, 0, 0, 0, 0};
            if (sp >= 0 && sp < SEQ) {
                const int t = tok[bat * SEQ + sp];
                v = *reinterpret_cast<const s16x8*>(embf + t * EMBD + c * 8);
            }
            int byte = row * 256 + c * 16;
            byte ^= (row & 7) << 4;
            *reinterpret_cast<s16x8*>(smem + byte) = v;
        }
    }
    __syncthreads();

    f32x4 acc2[4][2];                          // GEMM2 accumulator, carried across passes
    #pragma unroll
    for (int m = 0; m < 4; ++m)
        #pragma unroll
        for (int n = 0; n < 2; ++n) acc2[m][n] = (f32x4){0.f, 0.f, 0.f, 0.f};

    #pragma unroll
    for (int p = 0; p < 2; ++p) {
        // ---------- GEMM1 pass p: [64,640] x W1 cols [256p, 256p+256) -> h1 half in LDS B
        {
            f32x4 acc[4][2];
            #pragma unroll
            for (int m = 0; m < 4; ++m)
                #pragma unroll
                for (int n = 0; n < 2; ++n) acc[m][n] = (f32x4){0.f, 0.f, 0.f, 0.f};
            for (int ks = 0; ks < 20; ++ks) {
                const int j    = ks >> 2;
                const int doff = (ks & 3) * 32;
                s16x8 a[4];
                #pragma unroll
                for (int m = 0; m < 4; ++m) {
                    const int row = m * 16 + l15 + j;
                    int byte = row * 256 + (doff + 8 * l4) * 2;
                    byte ^= (row & 7) << 4;
                    a[m] = *reinterpret_cast<const s16x8*>(smem + byte);
                }
                #pragma unroll
                for (int n = 0; n < 2; ++n) {
                    const int ct = p * 16 + wave * 2 + n;
                    s16x8 b = *reinterpret_cast<const s16x8*>(
                        wbf + W1P + ((ct * 20 + ks) * 64 + lane) * 8);
                    #pragma unroll
                    for (int m = 0; m < 4; ++m)
                        acc[m][n] = __builtin_amdgcn_mfma_f32_16x16x32_bf16(a[m], b, acc[m][n], 0, 0, 0);
                }
            }
            // epilogue: bias + relu -> bf16 -> LDS region B (local cols 0..255)
            #pragma unroll
            for (int n = 0; n < 2; ++n) {
                const int col = p * 256 + wave * 32 + n * 16 + l15;
                const int lc  = wave * 32 + n * 16 + l15;
                const float bi = b1[col];
                #pragma unroll
                for (int m = 0; m < 4; ++m)
                    #pragma unroll
                    for (int q = 0; q < 4; ++q) {
                        const int row = m * 16 + l4 * 4 + q;
                        float v = fmaxf(acc[m][n][q] + bi, 0.f);
                        int byte = HB + row * 512 + lc * 2;
                        byte ^= (row & 7) << 4;
                        *reinterpret_cast<unsigned short*>(smem + byte) = (unsigned short)f2bf(v);
                    }
            }
        }
        __syncthreads();

        // ---------- GEMM2 partial: [64,256] (h1 half) x W2 k-range [256p,256p+256) -> acc2
        {
            for (int ks = 0; ks < 8; ++ks) {
                const int kl = ks * 32 + 8 * l4;
                s16x8 a[4];
                #pragma unroll
                for (int m = 0; m < 4; ++m) {
                    const int row = m * 16 + l15;
                    int byte = HB + row * 512 + kl * 2;
                    byte ^= (row & 7) << 4;
                    a[m] = *reinterpret_cast<const s16x8*>(smem + byte);
                }
                #pragma unroll
                for (int n = 0; n < 2; ++n) {
                    const int ct = wave * 2 + n;
                    s16x8 b = *reinterpret_cast<const s16x8*>(
                        wbf + W2P + ((ct * 16 + p * 8 + ks) * 64 + lane) * 8);
                    #pragma unroll
                    for (int m = 0; m < 4; ++m)
                        acc2[m][n] = __builtin_amdgcn_mfma_f32_16x16x32_bf16(a[m], b, acc2[m][n], 0, 0, 0);
                }
            }
        }
        __syncthreads();
    }

    // ---------- GEMM2 epilogue: bias + relu -> h2 bf16 in LDS region A
    {
        #pragma unroll
        for (int n = 0; n < 2; ++n) {
            const int col  = wave * 32 + n * 16 + l15;
            const float bi = b2[col];
            #pragma unroll
            for (int m = 0; m < 4; ++m)
                #pragma unroll
                for (int q = 0; q < 4; ++q) {
                    const int row = m * 16 + l4 * 4 + q;
                    float v = fmaxf(acc2[m][n][q] + bi, 0.f);
                    int byte = row * 512 + col * 2;
                    byte ^= (row & 7) << 4;
                    *reinterpret_cast<unsigned short*>(smem + byte) = (unsigned short)f2bf(v);
                }
        }
    }
    __syncthreads();

    // ---------- GEMM3: [64,256] x W3^T[256,128] -> h3 bf16 in LDS region B
    {
        f32x4 acc[4];
        #pragma unroll
        for (int m = 0; m < 4; ++m) acc[m] = (f32x4){0.f, 0.f, 0.f, 0.f};
        for (int ks = 0; ks < 8; ++ks) {
            const int kl = ks * 32 + 8 * l4;
            s16x8 b = *reinterpret_cast<const s16x8*>(
                wbf + W3P + ((wave * 8 + ks) * 64 + lane) * 8);
            #pragma unroll
            for (int m = 0; m < 4; ++m) {
                const int row = m * 16 + l15;
                int byte = row * 512 + kl * 2;
                byte ^= (row & 7) << 4;
                s16x8 a = *reinterpret_cast<const s16x8*>(smem + byte);
                acc[m] = __builtin_amdgcn_mfma_f32_16x16x32_bf16(a, b, acc[m], 0, 0, 0);
            }
        }
        const int col  = wave * 16 + l15;
        const float bi = b3[col];
        #pragma unroll
        for (int m = 0; m < 4; ++m)
            #pragma unroll
            for (int q = 0; q < 4; ++q) {
                const int row = m * 16 + l4 * 4 + q;
                float v = fmaxf(acc[m][q] + bi, 0.f);
                int byte = HB + row * 256 + col * 2;
                byte ^= (row & 7) << 4;
                *reinterpret_cast<unsigned short*>(smem + byte) = (unsigned short)f2bf(v);
            }
    }
    __syncthreads();

    // ---------- GEMM4: [64,128] x W4 (padded to 48 cols) -> out fp32 (waves 0..3)
    if (wave < 4) {
        f32x4 acc[3];
        #pragma unroll
        for (int n = 0; n < 3; ++n) acc[n] = (f32x4){0.f, 0.f, 0.f, 0.f};
        const int m = wave;
        #pragma unroll
        for (int ks = 0; ks < 4; ++ks) {
            const int kl  = ks * 32 + 8 * l4;
            const int row = m * 16 + l15;
            int byte = HB + row * 256 + kl * 2;
            byte ^= (row & 7) << 4;
            s16x8 a = *reinterpret_cast<const s16x8*>(smem + byte);
            #pragma unroll
            for (int n = 0; n < 3; ++n) {
                s16x8 b = *reinterpret_cast<const s16x8*>(
                    wbf + W4P + ((n * 4 + ks) * 64 + lane) * 8);
                acc[n] = __builtin_amdgcn_mfma_f32_16x16x32_bf16(a, b, acc[n], 0, 0, 0);
            }
        }
        #pragma unroll
        for (int n = 0; n < 3; ++n) {
            const int col = n * 16 + l15;
            if (col < 38) {
                const float bi = b4[col];
                #pragma unroll
                for (int q = 0; q < 4; ++q) {
                    const int rg = r0 + m * 16 + l4 * 4 + q;
                    out[rg * 38 + col] = acc[n][q] + bi;
                }
            }
        }
    }
}

extern "C" void kernel_launch(void* const* d_in, const int* in_sizes, int n_in,
                              void* d_out, int out_size, void* d_ws, size_t ws_size,
                              hipStream_t stream) {
    const int*   tok = (const int*)d_in[0];
    const float* emb = (const float*)d_in[1];
    const float* W1  = (const float*)d_in[2];
    const float* b1  = (const float*)d_in[3];
    const float* W2  = (const float*)d_in[4];
    const float* b2  = (const float*)d_in[5];
    const float* W3  = (const float*)d_in[6];
    const float* b3  = (const float*)d_in[7];
    const float* W4  = (const float*)d_in[8];
    const float* b4  = (const float*)d_in[9];
    float* out = (float*)d_out;
    unsigned short* wbf = (unsigned short*)d_ws;

    pack_kernel<<<(GTOT + 255) / 256, 256, 0, stream>>>(W1, W2, W3, W4, emb, wbf);
    fused_mlp<<<1024, 512, 0, stream>>>(tok, wbf, b1, b2, b3, b4, out);
}

// Round 5
// 79.121 us; speedup vs baseline: 2.9505x; 1.5294x over previous
//
#include <hip/hip_runtime.h>
#include <hip/hip_bf16.h>

#define SEQ 1024
#define EMBD 128

typedef __attribute__((ext_vector_type(8))) short s16x8;
typedef __attribute__((ext_vector_type(4))) float f32x4;

// packed bf16 offsets in workspace (elements)
// W layouts are MFMA-B-fragment linear: ((ctile*KC + kc)*64 + lane)*8
#define W1P 0
#define W2P (W1P + 32 * 20 * 512)
#define W3P (W2P + 16 * 16 * 512)
#define W4P (W3P + 8 * 8 * 512)
#define EMBP (W4P + 3 * 4 * 512)

#define G1N (32 * 20 * 64)
#define G2N (16 * 16 * 64)
#define G3N (8 * 8 * 64)
#define G4N (3 * 4 * 64)
#define GW  (G1N + G2N + G3N + G4N)
#define GEN (38 * 128 / 8)
#define GTOT (GW + GEN)

__device__ __forceinline__ unsigned int f2bf(float f) {
    unsigned int u = __float_as_uint(f);
    return (u + 0x7fffu + ((u >> 16) & 1u)) >> 16;   // RNE
}

__global__ void pack_kernel(const float* __restrict__ w1, const float* __restrict__ w2,
                            const float* __restrict__ w3, const float* __restrict__ w4,
                            const float* __restrict__ emb, unsigned short* __restrict__ dst) {
    const int g = blockIdx.x * 256 + threadIdx.x;
    if (g >= GTOT) return;
    unsigned short o[8];
    if (g < GW) {
        const float* w; int K, N, KC, base, gl;
        if (g < G1N)              { w = w1; K = 640; N = 512; KC = 20; base = W1P; gl = g; }
        else if (g < G1N + G2N)   { w = w2; K = 512; N = 256; KC = 16; base = W2P; gl = g - G1N; }
        else if (g < G1N+G2N+G3N) { w = w3; K = 256; N = 128; KC = 8;  base = W3P; gl = g - G1N - G2N; }
        else                      { w = w4; K = 128; N = 38;  KC = 4;  base = W4P; gl = g - G1N - G2N - G3N; }
        const int lane = gl & 63;
        const int t    = gl >> 6;
        const int ct   = t / KC;
        const int kc   = t - ct * KC;
        const int col  = ct * 16 + (lane & 15);
        const int k0   = kc * 32 + (lane >> 4) * 8;
        #pragma unroll
        for (int e = 0; e < 8; ++e)
            o[e] = (col < N) ? (unsigned short)f2bf(w[col * K + k0 + e]) : (unsigned short)0;
        *reinterpret_cast<s16x8*>(dst + base + (size_t)gl * 8) = *reinterpret_cast<s16x8*>(o);
    } else {
        const int gl = g - GW;
        #pragma unroll
        for (int e = 0; e < 8; ++e)
            o[e] = (unsigned short)f2bf(emb[gl * 8 + e]);
        *reinterpret_cast<s16x8*>(dst + EMBP + (size_t)gl * 8) = *reinterpret_cast<s16x8*>(o);
    }
}

// LDS layout (bytes), 96 KB total, 1024-thread block, 1 block/CU:
//   h1 @ 0      : 64 rows x 512 cols bf16, stride 1024  (65536 B)  -> later h3 (64x256B)
//   x  @ 65536  : 68 rows x 128 dims bf16, stride 256   (17408 B)
//   h2 @ 65536  : 64 rows x 256 cols bf16, stride 512   (32768 B)  (x dead after GEMM1)
#define H1S 0
#define XS  65536
#define H2S 65536
#define H3S 0

#define SWZ(b, row) ((b) ^ (((row) & 15) << 4))

__launch_bounds__(1024, 4)
__global__ void fused_mlp(const int* __restrict__ tok,
                          const unsigned short* __restrict__ wbf,
                          const float* __restrict__ b1,
                          const float* __restrict__ b2,
                          const float* __restrict__ b3,
                          const float* __restrict__ b4,
                          float* __restrict__ out) {
    __shared__ char smem[98304];
    const int tid  = threadIdx.x;
    const int lane = tid & 63;
    const int wave = tid >> 6;                 // 0..15
    const int l15  = lane & 15;
    const int l4   = lane >> 4;                // 0..3
    const int r0   = blockIdx.x * 64;
    const int s0   = r0 & (SEQ - 1);
    const int bat  = r0 >> 10;

    // ---------- stage embedded x tile: rows s0-2 .. s0+65 (68 rows) x 128 dims, bf16
    {
        const unsigned short* embf = wbf + EMBP;
        for (int chunk = tid; chunk < 68 * 16; chunk += 1024) {
            const int row = chunk >> 4;
            const int c   = chunk & 15;
            const int sp  = s0 - 2 + row;
            s16x8 v = {0, 0, 0, 0, 0, 0, 0, 0};
            if (sp >= 0 && sp < SEQ) {
                const int t = tok[bat * SEQ + sp];
                v = *reinterpret_cast<const s16x8*>(embf + t * EMBD + c * 8);
            }
            *reinterpret_cast<s16x8*>(smem + XS + SWZ(row * 256 + c * 16, row)) = v;
        }
    }
    __syncthreads();

    // ---------- GEMM1: [64,640] x W1^T -> h1 (full 512 cols) in LDS
    {
        f32x4 acc[4][2];
        #pragma unroll
        for (int m = 0; m < 4; ++m)
            #pragma unroll
            for (int n = 0; n < 2; ++n) acc[m][n] = (f32x4){0.f, 0.f, 0.f, 0.f};
        for (int ks = 0; ks < 20; ++ks) {
            const int j    = ks >> 2;
            const int doff = (ks & 3) * 32;
            s16x8 a[4];
            #pragma unroll
            for (int m = 0; m < 4; ++m) {
                const int row = m * 16 + l15 + j;
                a[m] = *reinterpret_cast<const s16x8*>(
                    smem + XS + SWZ(row * 256 + doff * 2 + l4 * 16, row));
            }
            #pragma unroll
            for (int n = 0; n < 2; ++n) {
                const int ct = wave * 2 + n;
                s16x8 b = *reinterpret_cast<const s16x8*>(
                    wbf + W1P + ((ct * 20 + ks) * 64 + lane) * 8);
                #pragma unroll
                for (int m = 0; m < 4; ++m)
                    acc[m][n] = __builtin_amdgcn_mfma_f32_16x16x32_bf16(a[m], b, acc[m][n], 0, 0, 0);
            }
        }
        #pragma unroll
        for (int n = 0; n < 2; ++n) {
            const int col  = wave * 32 + n * 16 + l15;
            const float bi = b1[col];
            #pragma unroll
            for (int m = 0; m < 4; ++m)
                #pragma unroll
                for (int q = 0; q < 4; ++q) {
                    const int row = m * 16 + l4 * 4 + q;
                    float v = fmaxf(acc[m][n][q] + bi, 0.f);
                    *reinterpret_cast<unsigned short*>(
                        smem + H1S + SWZ(row * 1024 + col * 2, row)) = (unsigned short)f2bf(v);
                }
        }
    }
    __syncthreads();

    // ---------- GEMM2: [64,512] x W2^T -> h2 in LDS (aliases x)
    {
        f32x4 acc[4];
        #pragma unroll
        for (int m = 0; m < 4; ++m) acc[m] = (f32x4){0.f, 0.f, 0.f, 0.f};
        for (int ks = 0; ks < 16; ++ks) {
            s16x8 a[4];
            #pragma unroll
            for (int m = 0; m < 4; ++m) {
                const int row = m * 16 + l15;
                a[m] = *reinterpret_cast<const s16x8*>(
                    smem + H1S + SWZ(row * 1024 + ks * 64 + l4 * 16, row));
            }
            s16x8 b = *reinterpret_cast<const s16x8*>(
                wbf + W2P + ((wave * 16 + ks) * 64 + lane) * 8);
            #pragma unroll
            for (int m = 0; m < 4; ++m)
                acc[m] = __builtin_amdgcn_mfma_f32_16x16x32_bf16(a[m], b, acc[m], 0, 0, 0);
        }
        const int col  = wave * 16 + l15;
        const float bi = b2[col];
        #pragma unroll
        for (int m = 0; m < 4; ++m)
            #pragma unroll
            for (int q = 0; q < 4; ++q) {
                const int row = m * 16 + l4 * 4 + q;
                float v = fmaxf(acc[m][q] + bi, 0.f);
                *reinterpret_cast<unsigned short*>(
                    smem + H2S + SWZ(row * 512 + col * 2, row)) = (unsigned short)f2bf(v);
            }
    }
    __syncthreads();

    // ---------- GEMM3: [64,256] x W3^T -> h3 in LDS (aliases h1)
    {
        const int mw = wave >> 3;              // row-half 0/1
        const int ct = wave & 7;               // col tile 0..7
        f32x4 acc[2];
        #pragma unroll
        for (int m = 0; m < 2; ++m) acc[m] = (f32x4){0.f, 0.f, 0.f, 0.f};
        for (int kc = 0; kc < 8; ++kc) {
            s16x8 b = *reinterpret_cast<const s16x8*>(
                wbf + W3P + ((ct * 8 + kc) * 64 + lane) * 8);
            #pragma unroll
            for (int m = 0; m < 2; ++m) {
                const int row = mw * 32 + m * 16 + l15;
                s16x8 a = *reinterpret_cast<const s16x8*>(
                    smem + H2S + SWZ(row * 512 + kc * 64 + l4 * 16, row));
                acc[m] = __builtin_amdgcn_mfma_f32_16x16x32_bf16(a, b, acc[m], 0, 0, 0);
            }
        }
        const int col  = ct * 16 + l15;
        const float bi = b3[col];
        #pragma unroll
        for (int m = 0; m < 2; ++m)
            #pragma unroll
            for (int q = 0; q < 4; ++q) {
                const int row = mw * 32 + m * 16 + l4 * 4 + q;
                float v = fmaxf(acc[m][q] + bi, 0.f);
                *reinterpret_cast<unsigned short*>(
                    smem + H3S + SWZ(row * 256 + col * 2, row)) = (unsigned short)f2bf(v);
            }
    }
    __syncthreads();

    // ---------- GEMM4: [64,128] x W4 (padded to 48 cols) -> out fp32 (waves 0..11)
    if (wave < 12) {
        const int m = wave & 3;
        const int n = wave >> 2;               // 0..2
        f32x4 acc = (f32x4){0.f, 0.f, 0.f, 0.f};
        #pragma unroll
        for (int ks = 0; ks < 4; ++ks) {
            const int row = m * 16 + l15;
            s16x8 a = *reinterpret_cast<const s16x8*>(
                smem + H3S + SWZ(row * 256 + ks * 64 + l4 * 16, row));
            s16x8 b = *reinterpret_cast<const s16x8*>(
                wbf + W4P + ((n * 4 + ks) * 64 + lane) * 8);
            acc = __builtin_amdgcn_mfma_f32_16x16x32_bf16(a, b, acc, 0, 0, 0);
        }
        const int col = n * 16 + l15;
        if (col < 38) {
            const float bi = b4[col];
            #pragma unroll
            for (int q = 0; q < 4; ++q) {
                const int rg = r0 + m * 16 + l4 * 4 + q;
                out[rg * 38 + col] = acc[q] + bi;
            }
        }
    }
}

extern "C" void kernel_launch(void* const* d_in, const int* in_sizes, int n_in,
                              void* d_out, int out_size, void* d_ws, size_t ws_size,
                              hipStream_t stream) {
    const int*   tok = (const int*)d_in[0];
    const float* emb = (const float*)d_in[1];
    const float* W1  = (const float*)d_in[2];
    const float* b1  = (const float*)d_in[3];
    const float* W2  = (const float*)d_in[4];
    const float* b2  = (const float*)d_in[5];
    const float* W3  = (const float*)d_in[6];
    const float* b3  = (const float*)d_in[7];
    const float* W4  = (const float*)d_in[8];
    const float* b4  = (const float*)d_in[9];
    float* out = (float*)d_out;
    unsigned short* wbf = (unsigned short*)d_ws;

    pack_kernel<<<(GTOT + 255) / 256, 256, 0, stream>>>(W1, W2, W3, W4, emb, wbf);
    fused_mlp<<<1024, 1024, 0, stream>>>(tok, wbf, b1, b2, b3, b4, out);
}

// Round 6
// 77.363 us; speedup vs baseline: 3.0175x; 1.0227x over previous
//
#include <hip/hip_runtime.h>
#include <hip/hip_bf16.h>

#define SEQ 1024
#define EMBD 128

typedef __attribute__((ext_vector_type(8))) short s16x8;
typedef __attribute__((ext_vector_type(4))) float f32x4;
typedef __attribute__((ext_vector_type(2))) unsigned int u32x2;
typedef __attribute__((ext_vector_type(2))) float f32x2;

// packed bf16 offsets in workspace (elements)
// W layouts are MFMA-fragment linear: ((ctile*KC + kc)*64 + lane)*8
// (same bytes serve as A-operand: row=lane&15, k=(lane>>4)*8+e)
#define W1P 0
#define W2P (W1P + 32 * 20 * 512)
#define W3P (W2P + 16 * 16 * 512)
#define W4P (W3P + 8 * 8 * 512)
#define EMBP (W4P + 3 * 4 * 512)

#define G1N (32 * 20 * 64)
#define G2N (16 * 16 * 64)
#define G3N (8 * 8 * 64)
#define G4N (3 * 4 * 64)
#define GW  (G1N + G2N + G3N + G4N)
#define GEN (38 * 128 / 8)
#define GTOT (GW + GEN)

__device__ __forceinline__ unsigned int f2bf(float f) {
    unsigned int u = __float_as_uint(f);
    return (u + 0x7fffu + ((u >> 16) & 1u)) >> 16;   // RNE
}

__global__ void pack_kernel(const float* __restrict__ w1, const float* __restrict__ w2,
                            const float* __restrict__ w3, const float* __restrict__ w4,
                            const float* __restrict__ emb, unsigned short* __restrict__ dst) {
    const int g = blockIdx.x * 256 + threadIdx.x;
    if (g >= GTOT) return;
    unsigned short o[8];
    if (g < GW) {
        const float* w; int K, N, KC, base, gl;
        if (g < G1N)              { w = w1; K = 640; N = 512; KC = 20; base = W1P; gl = g; }
        else if (g < G1N + G2N)   { w = w2; K = 512; N = 256; KC = 16; base = W2P; gl = g - G1N; }
        else if (g < G1N+G2N+G3N) { w = w3; K = 256; N = 128; KC = 8;  base = W3P; gl = g - G1N - G2N; }
        else                      { w = w4; K = 128; N = 38;  KC = 4;  base = W4P; gl = g - G1N - G2N - G3N; }
        const int lane = gl & 63;
        const int t    = gl >> 6;
        const int ct   = t / KC;
        const int kc   = t - ct * KC;
        const int col  = ct * 16 + (lane & 15);
        const int k0   = kc * 32 + (lane >> 4) * 8;
        #pragma unroll
        for (int e = 0; e < 8; ++e)
            o[e] = (col < N) ? (unsigned short)f2bf(w[col * K + k0 + e]) : (unsigned short)0;
        *reinterpret_cast<s16x8*>(dst + base + (size_t)gl * 8) = *reinterpret_cast<s16x8*>(o);
    } else {
        const int gl = g - GW;
        #pragma unroll
        for (int e = 0; e < 8; ++e)
            o[e] = (unsigned short)f2bf(emb[gl * 8 + e]);
        *reinterpret_cast<s16x8*>(dst + EMBP + (size_t)gl * 8) = *reinterpret_cast<s16x8*>(o);
    }
}

// LDS layout (bytes), 96 KB total, 1024-thread block, 1 block/CU:
//   h1 @ 0      : 64 rows x 512 cols bf16, stride 1024  (65536 B)  -> later h3 (64x256B)
//   x  @ 65536  : 68 rows x 128 dims bf16, stride 256   (17408 B)
//   h2 @ 65536  : 64 rows x 256 cols bf16, stride 512   (32768 B)  (x dead after GEMM1)
#define H1S 0
#define XS  65536
#define H2S 65536
#define H3S 0

#define SWZ(b, row) ((b) ^ (((row) & 15) << 4))

// pack 4 accum values (+bias, relu) into 2x u32 (4 bf16)
__device__ __forceinline__ u32x2 pack_relu(f32x4 a, float4 b) {
    unsigned int lo = f2bf(fmaxf(a[0] + b.x, 0.f)) | (f2bf(fmaxf(a[1] + b.y, 0.f)) << 16);
    unsigned int hi = f2bf(fmaxf(a[2] + b.z, 0.f)) | (f2bf(fmaxf(a[3] + b.w, 0.f)) << 16);
    return (u32x2){lo, hi};
}

__launch_bounds__(1024, 4)
__global__ void fused_mlp(const int* __restrict__ tok,
                          const unsigned short* __restrict__ wbf,
                          const float* __restrict__ b1,
                          const float* __restrict__ b2,
                          const float* __restrict__ b3,
                          const float* __restrict__ b4,
                          float* __restrict__ out) {
    __shared__ char smem[98304];
    const int tid  = threadIdx.x;
    const int lane = tid & 63;
    const int wave = tid >> 6;                 // 0..15
    const int l15  = lane & 15;
    const int l4   = lane >> 4;                // 0..3
    const int r0   = blockIdx.x * 64;
    const int s0   = r0 & (SEQ - 1);
    const int bat  = r0 >> 10;

    // ---------- stage embedded x tile: rows s0-2 .. s0+65 (68 rows) x 128 dims, bf16
    {
        const unsigned short* embf = wbf + EMBP;
        for (int chunk = tid; chunk < 68 * 16; chunk += 1024) {
            const int row = chunk >> 4;
            const int c   = chunk & 15;
            const int sp  = s0 - 2 + row;
            s16x8 v = {0, 0, 0, 0, 0, 0, 0, 0};
            if (sp >= 0 && sp < SEQ) {
                const int t = tok[bat * SEQ + sp];
                v = *reinterpret_cast<const s16x8*>(embf + t * EMBD + c * 8);
            }
            *reinterpret_cast<s16x8*>(smem + XS + SWZ(row * 256 + c * 16, row)) = v;
        }
    }
    __syncthreads();

    // ---------- GEMM1 (swapped): D[W1col][xrow], wave owns W-ctiles {2w,2w+1} x 4 row-tiles
    {
        f32x4 acc[4][2];
        #pragma unroll
        for (int n = 0; n < 4; ++n)
            #pragma unroll
            for (int mp = 0; mp < 2; ++mp) acc[n][mp] = (f32x4){0.f, 0.f, 0.f, 0.f};
        for (int ks = 0; ks < 20; ++ks) {
            const int j    = ks >> 2;
            const int doff = (ks & 3) * 32;
            s16x8 xv[4];
            #pragma unroll
            for (int n = 0; n < 4; ++n) {
                const int row = n * 16 + l15 + j;
                xv[n] = *reinterpret_cast<const s16x8*>(
                    smem + XS + SWZ(row * 256 + doff * 2 + l4 * 16, row));
            }
            #pragma unroll
            for (int mp = 0; mp < 2; ++mp) {
                const int ct = wave * 2 + mp;
                s16x8 w = *reinterpret_cast<const s16x8*>(
                    wbf + W1P + ((ct * 20 + ks) * 64 + lane) * 8);
                #pragma unroll
                for (int n = 0; n < 4; ++n)
                    acc[n][mp] = __builtin_amdgcn_mfma_f32_16x16x32_bf16(w, xv[n], acc[n][mp], 0, 0, 0);
            }
        }
        #pragma unroll
        for (int mp = 0; mp < 2; ++mp) {
            const int col0 = (wave * 2 + mp) * 16 + l4 * 4;
            const float4 bb = *reinterpret_cast<const float4*>(b1 + col0);
            #pragma unroll
            for (int n = 0; n < 4; ++n) {
                const int row = n * 16 + l15;
                *reinterpret_cast<u32x2*>(smem + H1S + SWZ(row * 1024 + col0 * 2, row)) =
                    pack_relu(acc[n][mp], bb);
            }
        }
    }
    __syncthreads();

    // ---------- GEMM2 (swapped): [64,512] -> [64,256]; wave owns W-ctile=wave x 4 row-tiles
    {
        f32x4 acc[4];
        #pragma unroll
        for (int n = 0; n < 4; ++n) acc[n] = (f32x4){0.f, 0.f, 0.f, 0.f};
        for (int ks = 0; ks < 16; ++ks) {
            s16x8 xv[4];
            #pragma unroll
            for (int n = 0; n < 4; ++n) {
                const int row = n * 16 + l15;
                xv[n] = *reinterpret_cast<const s16x8*>(
                    smem + H1S + SWZ(row * 1024 + ks * 64 + l4 * 16, row));
            }
            s16x8 w = *reinterpret_cast<const s16x8*>(
                wbf + W2P + ((wave * 16 + ks) * 64 + lane) * 8);
            #pragma unroll
            for (int n = 0; n < 4; ++n)
                acc[n] = __builtin_amdgcn_mfma_f32_16x16x32_bf16(w, xv[n], acc[n], 0, 0, 0);
        }
        const int col0 = wave * 16 + l4 * 4;
        const float4 bb = *reinterpret_cast<const float4*>(b2 + col0);
        #pragma unroll
        for (int n = 0; n < 4; ++n) {
            const int row = n * 16 + l15;
            *reinterpret_cast<u32x2*>(smem + H2S + SWZ(row * 512 + col0 * 2, row)) =
                pack_relu(acc[n], bb);
        }
    }
    __syncthreads();

    // ---------- GEMM3 (swapped): [64,256] -> [64,128]; wave: ct=wave&7, row-half=wave>>3
    {
        const int ct = wave & 7;
        const int nh = wave >> 3;              // 0/1 -> rows [nh*32, nh*32+32)
        f32x4 acc[2];
        #pragma unroll
        for (int i = 0; i < 2; ++i) acc[i] = (f32x4){0.f, 0.f, 0.f, 0.f};
        for (int ks = 0; ks < 8; ++ks) {
            s16x8 w = *reinterpret_cast<const s16x8*>(
                wbf + W3P + ((ct * 8 + ks) * 64 + lane) * 8);
            #pragma unroll
            for (int i = 0; i < 2; ++i) {
                const int row = (nh * 2 + i) * 16 + l15;
                s16x8 xv = *reinterpret_cast<const s16x8*>(
                    smem + H2S + SWZ(row * 512 + ks * 64 + l4 * 16, row));
                acc[i] = __builtin_amdgcn_mfma_f32_16x16x32_bf16(w, xv, acc[i], 0, 0, 0);
            }
        }
        const int col0 = ct * 16 + l4 * 4;
        const float4 bb = *reinterpret_cast<const float4*>(b3 + col0);
        #pragma unroll
        for (int i = 0; i < 2; ++i) {
            const int row = (nh * 2 + i) * 16 + l15;
            *reinterpret_cast<u32x2*>(smem + H3S + SWZ(row * 256 + col0 * 2, row)) =
                pack_relu(acc[i], bb);
        }
    }
    __syncthreads();

    // ---------- GEMM4 (swapped): [64,128] -> out[64,38]; waves 0..11: mt=w>>2, n=w&3
    if (wave < 12) {
        const int mt = wave >> 2;              // W4 col tile 0..2
        const int n  = wave & 3;               // row tile
        f32x4 acc = (f32x4){0.f, 0.f, 0.f, 0.f};
        #pragma unroll
        for (int ks = 0; ks < 4; ++ks) {
            const int row = n * 16 + l15;
            s16x8 xv = *reinterpret_cast<const s16x8*>(
                smem + H3S + SWZ(row * 256 + ks * 64 + l4 * 16, row));
            s16x8 w = *reinterpret_cast<const s16x8*>(
                wbf + W4P + ((mt * 4 + ks) * 64 + lane) * 8);
            acc = __builtin_amdgcn_mfma_f32_16x16x32_bf16(w, xv, acc, 0, 0, 0);
        }
        const int rg   = r0 + n * 16 + l15;
        const int col0 = mt * 16 + l4 * 4;
        #pragma unroll
        for (int h = 0; h < 2; ++h) {
            const int c = col0 + 2 * h;
            if (c < 38) {
                f32x2 v;
                v[0] = acc[2 * h]     + b4[c];
                v[1] = acc[2 * h + 1] + b4[c + 1];
                *reinterpret_cast<f32x2*>(out + rg * 38 + c) = v;
            }
        }
    }
}

extern "C" void kernel_launch(void* const* d_in, const int* in_sizes, int n_in,
                              void* d_out, int out_size, void* d_ws, size_t ws_size,
                              hipStream_t stream) {
    const int*   tok = (const int*)d_in[0];
    const float* emb = (const float*)d_in[1];
    const float* W1  = (const float*)d_in[2];
    const float* b1  = (const float*)d_in[3];
    const float* W2  = (const float*)d_in[4];
    const float* b2  = (const float*)d_in[5];
    const float* W3  = (const float*)d_in[6];
    const float* b3  = (const float*)d_in[7];
    const float* W4  = (const float*)d_in[8];
    const float* b4  = (const float*)d_in[9];
    float* out = (float*)d_out;
    unsigned short* wbf = (unsigned short*)d_ws;

    pack_kernel<<<(GTOT + 255) / 256, 256, 0, stream>>>(W1, W2, W3, W4, emb, wbf);
    fused_mlp<<<1024, 1024, 0, stream>>>(tok, wbf, b1, b2, b3, b4, out);
}

// Round 8
// 54.193 us; speedup vs baseline: 4.3076x; 1.4275x over previous
//
#include <hip/hip_runtime.h>
#include <hip/hip_bf16.h>

#define SEQ 1024

typedef __attribute__((ext_vector_type(8))) short s16x8;
typedef __attribute__((ext_vector_type(4))) float f32x4;
typedef __attribute__((ext_vector_type(2))) unsigned int u32x2;
typedef __attribute__((ext_vector_type(4))) unsigned int u32x4;
typedef __attribute__((ext_vector_type(2))) float f32x2;

// workspace layout (bf16 elements)
//  G table: [5][39][512]  (v=38 is the zero/padding row)
#define GT  0
#define W2P (5 * 39 * 512)
#define W3P (W2P + 16 * 16 * 512)
#define W4P (W3P + 8 * 8 * 512)

// pack frag-groups (64 lanes x 8 elems each) for W2/W3/W4, 16x16 MFMA layout
#define F2 (16 * 16)
#define F3 (8 * 8)
#define F4 (3 * 4)
#define FTOT (F2 + F3 + F4)
#define GC_BLOCKS 195   // 5*39 G-table blocks

__device__ __forceinline__ unsigned int f2bf(float f) {
    unsigned int u = __float_as_uint(f);
    return (u + 0x7fffu + ((u >> 16) & 1u)) >> 16;   // RNE
}

__device__ __forceinline__ unsigned short bfbits(float f) {
    __hip_bfloat16 h = __float2bfloat16(f);          // HW RNE cvt
    unsigned short u;
    __builtin_memcpy(&u, &h, 2);
    return u;
}

__device__ __forceinline__ unsigned pk2(float a, float b) {
    return (unsigned)bfbits(a) | ((unsigned)bfbits(b) << 16);
}

// prep: blocks [0,195) compute G[j][v][o] = dot(W1[o][j*128..], emb[v]); rest pack W2/3/4
__global__ void prep_kernel(const float* __restrict__ w1, const float* __restrict__ w2,
                            const float* __restrict__ w3, const float* __restrict__ w4,
                            const float* __restrict__ emb, unsigned short* __restrict__ dst) {
    if (blockIdx.x < GC_BLOCKS) {
        const int j = blockIdx.x / 39;
        const int v = blockIdx.x % 39;
        const int o = threadIdx.x;               // 0..511
        if (v >= 38) {                           // zero padding row (uniform per block)
            dst[GT + (j * 39 + v) * 512 + o] = 0;
            return;
        }
        __shared__ float ev[128];
        if (threadIdx.x < 128) ev[threadIdx.x] = emb[v * 128 + threadIdx.x];
        __syncthreads();
        const float* wr = w1 + o * 640 + j * 128;
        float s = 0.f;
        #pragma unroll
        for (int e = 0; e < 128; e += 4) {
            const float4 a = *reinterpret_cast<const float4*>(wr + e);
            s += a.x * ev[e] + a.y * ev[e + 1] + a.z * ev[e + 2] + a.w * ev[e + 3];
        }
        dst[GT + (j * 39 + v) * 512 + o] = bfbits(s);
    } else {
        const int g = (blockIdx.x - GC_BLOCKS) * 512 + threadIdx.x;
        if (g >= FTOT * 64) return;
        const int lane = g & 63;
        const int t    = g >> 6;
        const float* w; int K, N, KC, base, tl;
        if (t < F2)           { w = w2; K = 512; N = 256; KC = 16; base = W2P; tl = t; }
        else if (t < F2 + F3) { w = w3; K = 256; N = 128; KC = 8;  base = W3P; tl = t - F2; }
        else                  { w = w4; K = 128; N = 38;  KC = 4;  base = W4P; tl = t - F2 - F3; }
        const int ct  = tl / KC;
        const int kc  = tl - ct * KC;
        const int col = ct * 16 + (lane & 15);
        const int k0  = kc * 32 + (lane >> 4) * 8;
        unsigned short o8[8];
        #pragma unroll
        for (int e = 0; e < 8; ++e)
            o8[e] = (col < N) ? (unsigned short)f2bf(w[col * K + k0 + e]) : (unsigned short)0;
        // NOTE: index with tl (per-matrix), not t (global) — R6 bug wrote W3/W4 out of region
        *reinterpret_cast<s16x8*>(dst + base + (size_t)(tl * 64 + lane) * 8) =
            *reinterpret_cast<s16x8*>(o8);
    }
}

// LDS layout (bytes), 96 KB, 1024-thread block, 1 block/CU:
//   h1 @ 0      : 64 rows x 512 cols bf16, stride 1024  (65536 B)  -> later h3 (64x256B)
//   h2 @ 65536  : 64 rows x 256 cols bf16, stride 512   (32768 B)
//   tokLDS @ 65536 during phase 1 (h2 region free until GEMM2 epilogue)
#define H1S 0
#define H2S 65536
#define H3S 0

#define SWZ(b, row) ((b) ^ (((row) & 15) << 4))

__device__ __forceinline__ u32x2 pack_relu(f32x4 a, float4 b) {
    u32x2 r;
    r[0] = pk2(fmaxf(a[0] + b.x, 0.f), fmaxf(a[1] + b.y, 0.f));
    r[1] = pk2(fmaxf(a[2] + b.z, 0.f), fmaxf(a[3] + b.w, 0.f));
    return r;
}

__launch_bounds__(1024, 4)
__global__ void fused_mlp(const int* __restrict__ tok,
                          const unsigned short* __restrict__ wbf,
                          const float* __restrict__ b1,
                          const float* __restrict__ b2,
                          const float* __restrict__ b3,
                          const float* __restrict__ b4,
                          float* __restrict__ out) {
    __shared__ char smem[98304];
    const int tid  = threadIdx.x;
    const int lane = tid & 63;
    const int wave = tid >> 6;                 // 0..15
    const int l15  = lane & 15;
    const int l4   = lane >> 4;                // 0..3
    const int r0   = blockIdx.x * 64;
    const int s0   = r0 & (SEQ - 1);
    const int bat  = r0 >> 10;

    int* tokLDS = reinterpret_cast<int*>(smem + H2S);

    // ---------- stage context tokens (OOB -> 38, the zero G row)
    if (tid < 68) {
        const int sp = s0 - 2 + tid;
        tokLDS[tid] = (sp >= 0 && sp < SEQ) ? tok[bat * SEQ + sp] : 38;
    }
    __syncthreads();

    // ---------- phase 1: h1[row][c*8..+8] = relu(b1 + sum_j G[j][tok[row+j]]) -> LDS bf16
    {
        const unsigned short* gt = wbf + GT;
        #pragma unroll
        for (int it = 0; it < 4; ++it) {
            const int item = it * 1024 + tid;  // 0..4095
            const int row  = item >> 6;        // 0..63
            const int c    = item & 63;        // 8-dim chunk
            float s[8];
            {
                const float4 blo = *reinterpret_cast<const float4*>(b1 + c * 8);
                const float4 bhi = *reinterpret_cast<const float4*>(b1 + c * 8 + 4);
                s[0] = blo.x; s[1] = blo.y; s[2] = blo.z; s[3] = blo.w;
                s[4] = bhi.x; s[5] = bhi.y; s[6] = bhi.z; s[7] = bhi.w;
            }
            #pragma unroll
            for (int j = 0; j < 5; ++j) {
                const int t = tokLDS[row + j];
                const s16x8 g = *reinterpret_cast<const s16x8*>(gt + (j * 39 + t) * 512 + c * 8);
                #pragma unroll
                for (int e = 0; e < 8; ++e)
                    s[e] += __uint_as_float(((unsigned)(unsigned short)g[e]) << 16);
            }
            u32x4 wv;
            #pragma unroll
            for (int h = 0; h < 4; ++h)
                wv[h] = pk2(fmaxf(s[2 * h], 0.f), fmaxf(s[2 * h + 1], 0.f));
            *reinterpret_cast<u32x4*>(smem + H1S + SWZ(row * 1024 + c * 16, row)) = wv;
        }
    }
    __syncthreads();

    // ---------- GEMM2 (swapped): [64,512] -> [64,256]; wave owns W-ctile=wave x 4 row-tiles
    {
        f32x4 acc[4];
        #pragma unroll
        for (int n = 0; n < 4; ++n) acc[n] = (f32x4){0.f, 0.f, 0.f, 0.f};
        for (int ks = 0; ks < 16; ++ks) {
            s16x8 xv[4];
            #pragma unroll
            for (int n = 0; n < 4; ++n) {
                const int row = n * 16 + l15;
                xv[n] = *reinterpret_cast<const s16x8*>(
                    smem + H1S + SWZ(row * 1024 + ks * 64 + l4 * 16, row));
            }
            s16x8 w = *reinterpret_cast<const s16x8*>(
                wbf + W2P + ((wave * 16 + ks) * 64 + lane) * 8);
            #pragma unroll
            for (int n = 0; n < 4; ++n)
                acc[n] = __builtin_amdgcn_mfma_f32_16x16x32_bf16(w, xv[n], acc[n], 0, 0, 0);
        }
        const int col0 = wave * 16 + l4 * 4;
        const float4 bb = *reinterpret_cast<const float4*>(b2 + col0);
        #pragma unroll
        for (int n = 0; n < 4; ++n) {
            const int row = n * 16 + l15;
            *reinterpret_cast<u32x2*>(smem + H2S + SWZ(row * 512 + col0 * 2, row)) =
                pack_relu(acc[n], bb);
        }
    }
    __syncthreads();

    // ---------- GEMM3 (swapped): [64,256] -> [64,128]; wave: ct=wave&7, row-half=wave>>3
    {
        const int ct = wave & 7;
        const int nh = wave >> 3;              // 0/1 -> rows [nh*32, nh*32+32)
        f32x4 acc[2];
        #pragma unroll
        for (int i = 0; i < 2; ++i) acc[i] = (f32x4){0.f, 0.f, 0.f, 0.f};
        for (int ks = 0; ks < 8; ++ks) {
            s16x8 w = *reinterpret_cast<const s16x8*>(
                wbf + W3P + ((ct * 8 + ks) * 64 + lane) * 8);
            #pragma unroll
            for (int i = 0; i < 2; ++i) {
                const int row = (nh * 2 + i) * 16 + l15;
                s16x8 xv = *reinterpret_cast<const s16x8*>(
                    smem + H2S + SWZ(row * 512 + ks * 64 + l4 * 16, row));
                acc[i] = __builtin_amdgcn_mfma_f32_16x16x32_bf16(w, xv, acc[i], 0, 0, 0);
            }
        }
        const int col0 = ct * 16 + l4 * 4;
        const float4 bb = *reinterpret_cast<const float4*>(b3 + col0);
        #pragma unroll
        for (int i = 0; i < 2; ++i) {
            const int row = (nh * 2 + i) * 16 + l15;
            *reinterpret_cast<u32x2*>(smem + H3S + SWZ(row * 256 + col0 * 2, row)) =
                pack_relu(acc[i], bb);
        }
    }
    __syncthreads();

    // ---------- GEMM4 (swapped): [64,128] -> out[64,38]; waves 0..11: mt=w>>2, n=w&3
    if (wave < 12) {
        const int mt = wave >> 2;              // W4 col tile 0..2
        const int n  = wave & 3;               // row tile
        f32x4 acc = (f32x4){0.f, 0.f, 0.f, 0.f};
        #pragma unroll
        for (int ks = 0; ks < 4; ++ks) {
            const int row = n * 16 + l15;
            s16x8 xv = *reinterpret_cast<const s16x8*>(
                smem + H3S + SWZ(row * 256 + ks * 64 + l4 * 16, row));
            s16x8 w = *reinterpret_cast<const s16x8*>(
                wbf + W4P + ((mt * 4 + ks) * 64 + lane) * 8);
            acc = __builtin_amdgcn_mfma_f32_16x16x32_bf16(w, xv, acc, 0, 0, 0);
        }
        const int rg   = r0 + n * 16 + l15;
        const int col0 = mt * 16 + l4 * 4;
        #pragma unroll
        for (int h = 0; h < 2; ++h) {
            const int c = col0 + 2 * h;
            if (c < 38) {
                f32x2 v;
                v[0] = acc[2 * h]     + b4[c];
                v[1] = acc[2 * h + 1] + b4[c + 1];
                *reinterpret_cast<f32x2*>(out + rg * 38 + c) = v;
            }
        }
    }
}

extern "C" void kernel_launch(void* const* d_in, const int* in_sizes, int n_in,
                              void* d_out, int out_size, void* d_ws, size_t ws_size,
                              hipStream_t stream) {
    const int*   tok = (const int*)d_in[0];
    const float* emb = (const float*)d_in[1];
    const float* W1  = (const float*)d_in[2];
    const float* b1  = (const float*)d_in[3];
    const float* W2  = (const float*)d_in[4];
    const float* b2  = (const float*)d_in[5];
    const float* W3  = (const float*)d_in[6];
    const float* b3  = (const float*)d_in[7];
    const float* W4  = (const float*)d_in[8];
    const float* b4  = (const float*)d_in[9];
    float* out = (float*)d_out;
    unsigned short* wbf = (unsigned short*)d_ws;

    const int pack_blocks = (FTOT * 64 + 511) / 512;     // 42
    prep_kernel<<<GC_BLOCKS + pack_blocks, 512, 0, stream>>>(W1, W2, W3, W4, emb, wbf);
    fused_mlp<<<1024, 1024, 0, stream>>>(tok, wbf, b1, b2, b3, b4, out);
}